// Round 8
// baseline (1792.167 us; speedup 1.0000x reference)
//
#include <hip/hip_runtime.h>
#include <hip/hip_bf16.h>
#include <math.h>

// ---------------------------------------------------------------------------
// three_gcn round 8: sort-free aggregation.
//   - bucket_scatter v2: LDS-staged bucketing of packed (dstlocal<<17|src)
//     records into 256-dst buckets; coalesced run writes (no counting sort:
//     aggregation is order-agnostic, so sorting within buckets was wasted).
//   - per layer: gemm (h_rel = x@W_rel, bf16 MFMA)
//                bucket_agg: [root MFMA + bias -> LDS f32 acc] then
//                [edge loop: gather hrel rows, ds_add_f32 accumulate] then
//                [activation + coalesced store]. hroot buffer eliminated.
// ---------------------------------------------------------------------------

#define D 64
#define EPB 16384      // edges per scatter block
#define BCAP 4096      // records per bucket (mean 3200, +15 sigma)
#define MAXNB 512      // bucket array size (nb = 391 at n=100000)

typedef __attribute__((ext_vector_type(8))) short short8;
typedef __attribute__((ext_vector_type(4))) float f32x4;

__device__ __forceinline__ ushort f2b(float f) {
    uint x = __float_as_uint(f);
    uint r = (x + 0x7fffu + ((x >> 16) & 1u)) >> 16;   // RNE
    return (ushort)r;
}

// ---------------- weight convert + bucketCnt zero ----------------

__global__ __launch_bounds__(256) void convert_w(const float* __restrict__ w0,
                                                 const float* __restrict__ w1,
                                                 const float* __restrict__ w2,
                                                 const float* __restrict__ w3,
                                                 const float* __restrict__ w4,
                                                 const float* __restrict__ w5,
                                                 ushort* __restrict__ out,
                                                 int* __restrict__ bucketCnt) {
    if (blockIdx.x == 0) {
        for (int i = threadIdx.x; i < MAXNB; i += 256) bucketCnt[i] = 0;
    }
    int m = blockIdx.x >> 4;
    int t = (blockIdx.x & 15) * 256 + threadIdx.x;   // 0..4095
    const float* src = m == 0 ? w0 : m == 1 ? w1 : m == 2 ? w2 : m == 3 ? w3 : m == 4 ? w4 : w5;
    int k = t >> 6, d = t & 63;
    out[m * 4096 + d * 64 + k] = f2b(src[t]);
}

// ---------------- bucket scatter v2 (LDS-staged) ----------------
// 1024 threads, 16384 edges/block held in registers; LDS hist over nb
// buckets; in-LDS scatter ordered by bucket; then per-bucket runs (avg 42
// recs) copied to global at atomically reserved bases. Record = dl<<17 | src
// (src < 2^17, dl < 256).

__global__ __launch_bounds__(1024) void bucket_scatter(const int* __restrict__ src,
                                                       const int* __restrict__ dst,
                                                       int* __restrict__ bucketCnt,
                                                       uint* __restrict__ store,
                                                       int E, int nb) {
    __shared__ uint recs[EPB];                       // 64 KB
    __shared__ int h[MAXNB], loc[MAXNB], cur[MAXNB], gbase[MAXNB], sc[MAXNB];
    int t = threadIdx.x;
    for (int i = t; i < MAXNB; i += 1024) { h[i] = 0; cur[i] = 0; }
    __syncthreads();

    int e0 = blockIdx.x * EPB;
    int cntB = E - e0; if (cntB > EPB) cntB = EPB;

    uint rb[16]; int bb[16];
#pragma unroll
    for (int i = 0; i < 16; ++i) {
        int idx = i * 1024 + t;
        if (idx < cntB) {
            int e = e0 + idx;
            int d = dst[e], s = src[e];
            bb[i] = d >> 8;
            rb[i] = ((uint)(d & 255) << 17) | (uint)s;
            atomicAdd(&h[bb[i]], 1);
        } else bb[i] = -1;
    }
    __syncthreads();

    // exclusive scan over MAXNB (padded) counters
    if (t < MAXNB) sc[t] = h[t];
    __syncthreads();
    for (int off = 1; off < MAXNB; off <<= 1) {
        int add = (t < MAXNB && t >= off) ? sc[t - off] : 0;
        __syncthreads();
        if (t < MAXNB) sc[t] += add;
        __syncthreads();
    }
    if (t < MAXNB) {
        loc[t] = sc[t] - h[t];
        gbase[t] = h[t] ? atomicAdd(&bucketCnt[t], h[t]) : 0;
    }
    __syncthreads();

    // scatter into LDS, grouped by bucket
#pragma unroll
    for (int i = 0; i < 16; ++i) {
        if (bb[i] >= 0) {
            int p = atomicAdd(&cur[bb[i]], 1);
            recs[loc[bb[i]] + p] = rb[i];
        }
    }
    __syncthreads();

    // copy runs out: wave wv handles buckets wv, wv+16, ...
    int wv = t >> 6, l = t & 63;
    for (int b = wv; b < nb; b += 16) {
        int c = h[b], lb = loc[b], gb = gbase[b];
        uint* bst = store + (size_t)b * BCAP;
        for (int i = l; i < c; i += 64) {
            int pos = gb + i;
            if (pos < BCAP) bst[pos] = recs[lb + i];
        }
    }
}

// ---------------- gemm: h_rel = x @ W_rel (bf16 MFMA) ----------------

__global__ __launch_bounds__(256) void gemm(const float* __restrict__ x,
                                            const ushort* __restrict__ WtR,
                                            ushort* __restrict__ hrel, int n) {
    __shared__ ushort hs[4][16 * 64];
    int t = threadIdx.x;
    int w = t >> 6, l = t & 63;
    int i0 = blockIdx.x * 64 + w * 16;
    int lr = l & 15, kb = l >> 4;
    int row = i0 + lr;
    int rowc = row < n ? row : n - 1;

    short8 a[2];
#pragma unroll
    for (int s = 0; s < 2; ++s) {
        const float* p = x + (size_t)rowc * D + s * 32 + kb * 8;
        float4 u = *(const float4*)p;
        float4 v = *(const float4*)(p + 4);
        a[s][0] = f2b(u.x); a[s][1] = f2b(u.y); a[s][2] = f2b(u.z); a[s][3] = f2b(u.w);
        a[s][4] = f2b(v.x); a[s][5] = f2b(v.y); a[s][6] = f2b(v.z); a[s][7] = f2b(v.w);
    }

#pragma unroll
    for (int ct = 0; ct < 4; ++ct) {
        f32x4 acc = (f32x4){0.f, 0.f, 0.f, 0.f};
#pragma unroll
        for (int s = 0; s < 2; ++s) {
            short8 b = *(const short8*)(WtR + (ct * 16 + lr) * D + s * 32 + kb * 8);
            acc = __builtin_amdgcn_mfma_f32_16x16x32_bf16(a[s], b, acc, 0, 0, 0);
        }
#pragma unroll
        for (int i = 0; i < 4; ++i)
            hs[w][(kb * 4 + i) * 64 + ct * 16 + lr] = f2b(acc[i]);
    }
    __syncthreads();

    int r = l >> 2, ch = l & 3;
    int grow = i0 + r;
    if (grow < n) {
        const float4* sp = (const float4*)&hs[w][r * 64 + ch * 16];
        float4 v0 = sp[0];
        float4 v1 = sp[1];
        *(float4*)(hrel + (size_t)grow * D + ch * 16) = v0;
        *(float4*)(hrel + (size_t)grow * D + ch * 16 + 8) = v1;
    }
}

// ---------------- bucket_agg: fused root-GEMM + edge accumulate + act ------
// One block (1024 thr, 16 waves) per 256-dst bucket.
//   A: acc[node][dim] = (x@W_root)[node][dim] + bias[dim]   (MFMA -> LDS f32)
//   B: for each bucket record (dl,src): acc[dl][:] += hrel[src][:]
//      4 edges/wave: q=l>>4 edge slot, r=l&15 dims 4r..4r+3; ds_add_f32 x4.
//   C: y[d0+node][dim] = act(acc[node][dim])   (coalesced float4 stores)

template <int ACT>
__global__ __launch_bounds__(1024) void bucket_agg(const float* __restrict__ x,
                                                   const ushort* __restrict__ hrel,
                                                   const ushort* __restrict__ WtO,
                                                   const float* __restrict__ bias,
                                                   const uint* __restrict__ store,
                                                   const int* __restrict__ bucketCnt,
                                                   float* __restrict__ y, int n) {
    __shared__ float accL[256 * 64];                 // 64 KB
    int b = blockIdx.x, t = threadIdx.x;
    int d0 = b << 8;
    int nd = n - d0; if (nd > 256) nd = 256;
    int wv = t >> 6, l = t & 63;
    int lr = l & 15, kb = l >> 4;

    // ---- phase A: root term + bias ----
    {
        int row = d0 + wv * 16 + lr;
        int rowc = row < n ? row : n - 1;
        short8 a[2];
#pragma unroll
        for (int s = 0; s < 2; ++s) {
            const float* p = x + (size_t)rowc * D + s * 32 + kb * 8;
            float4 u = *(const float4*)p;
            float4 v = *(const float4*)(p + 4);
            a[s][0] = f2b(u.x); a[s][1] = f2b(u.y); a[s][2] = f2b(u.z); a[s][3] = f2b(u.w);
            a[s][4] = f2b(v.x); a[s][5] = f2b(v.y); a[s][6] = f2b(v.z); a[s][7] = f2b(v.w);
        }
#pragma unroll
        for (int ct = 0; ct < 4; ++ct) {
            f32x4 acc = (f32x4){0.f, 0.f, 0.f, 0.f};
#pragma unroll
            for (int s = 0; s < 2; ++s) {
                short8 bO = *(const short8*)(WtO + (ct * 16 + lr) * D + s * 32 + kb * 8);
                acc = __builtin_amdgcn_mfma_f32_16x16x32_bf16(a[s], bO, acc, 0, 0, 0);
            }
            float bv = bias[ct * 16 + lr];
#pragma unroll
            for (int i = 0; i < 4; ++i)
                accL[(wv * 16 + kb * 4 + i) * 64 + ct * 16 + lr] = acc[i] + bv;
        }
    }
    __syncthreads();

    // ---- phase B: accumulate edges ----
    {
        int cnt = bucketCnt[b]; if (cnt > BCAP) cnt = BCAP;
        const uint* bst = store + (size_t)b * BCAP;
        int q = l >> 4, r = l & 15;
        for (int e0 = 0; e0 < cnt; e0 += 64) {
            int e = e0 + wv * 4 + q;
            if (e < cnt) {
                uint rec = bst[e];
                int s = rec & 0x1FFFF;
                int dl = rec >> 17;
                uint2 u = *(const uint2*)(hrel + (size_t)s * D + r * 4);
                float* ap = &accL[dl * 64 + r * 4];
                atomicAdd(ap + 0, __uint_as_float(u.x << 16));
                atomicAdd(ap + 1, __uint_as_float(u.x & 0xffff0000u));
                atomicAdd(ap + 2, __uint_as_float(u.y << 16));
                atomicAdd(ap + 3, __uint_as_float(u.y & 0xffff0000u));
            }
        }
    }
    __syncthreads();

    // ---- phase C: activation + store ----
#pragma unroll
    for (int it = 0; it < 4; ++it) {
        int idx = it * 1024 + t;       // 0..4095
        int node = idx >> 4;
        int ch = idx & 15;
        if (node < nd) {
            float4 v = *(const float4*)&accL[node * 64 + ch * 4];
            if (ACT == 0) {
                v.x = v.x > 0.f ? v.x : __expf(v.x) - 1.f;
                v.y = v.y > 0.f ? v.y : __expf(v.y) - 1.f;
                v.z = v.z > 0.f ? v.z : __expf(v.z) - 1.f;
                v.w = v.w > 0.f ? v.w : __expf(v.w) - 1.f;
            } else {
                v.x = __builtin_amdgcn_rcpf(1.f + __expf(-v.x));
                v.y = __builtin_amdgcn_rcpf(1.f + __expf(-v.y));
                v.z = __builtin_amdgcn_rcpf(1.f + __expf(-v.z));
                v.w = __builtin_amdgcn_rcpf(1.f + __expf(-v.w));
            }
            *(float4*)(y + (size_t)(d0 + node) * D + ch * 4) = v;
        }
    }
}

// ---------------- launch ----------------

extern "C" void kernel_launch(void* const* d_in, const int* in_sizes, int n_in,
                              void* d_out, int out_size, void* d_ws, size_t ws_size,
                              hipStream_t stream) {
    const float* graph = (const float*)d_in[0];
    const int* eidx    = (const int*)d_in[1];
    const float* W1r = (const float*)d_in[2];
    const float* W1o = (const float*)d_in[3];
    const float* b1  = (const float*)d_in[4];
    const float* W2r = (const float*)d_in[5];
    const float* W2o = (const float*)d_in[6];
    const float* b2  = (const float*)d_in[7];
    const float* W3r = (const float*)d_in[8];
    const float* W3o = (const float*)d_in[9];
    const float* b3  = (const float*)d_in[10];

    int n = in_sizes[0] / D;     // 100000
    int E = in_sizes[1] / 2;     // 1250000
    const int* src  = eidx;
    const int* dstl = eidx + E;
    int nb = (n + 255) >> 8;     // 391

    char* w = (char*)d_ws;
    auto carve = [&](size_t bytes) {
        void* p = (void*)w;
        w += (bytes + 255) & ~(size_t)255;
        return p;
    };
    ushort* hrel   = (ushort*)carve((size_t)n * D * sizeof(ushort));   // 12.8 MB
    uint* store    = (uint*)carve((size_t)MAXNB * BCAP * sizeof(uint)); // 8 MB
    int* bucketCnt = (int*)carve(MAXNB * sizeof(int));
    ushort* wt     = (ushort*)carve(6 * 4096 * sizeof(ushort));        // 48 KB
    ushort* wtR1 = wt;
    ushort* wtO1 = wt + 1 * 4096;
    ushort* wtR2 = wt + 2 * 4096;
    ushort* wtO2 = wt + 3 * 4096;
    ushort* wtR3 = wt + 4 * 4096;
    ushort* wtO3 = wt + 5 * 4096;

    int sbk = (E + EPB - 1) / EPB;   // 77
    int tb  = (n + 63) / 64;         // 1563

    convert_w<<<96, 256, 0, stream>>>(W1r, W1o, W2r, W2o, W3r, W3o, wt, bucketCnt);
    bucket_scatter<<<sbk, 1024, 0, stream>>>(src, dstl, bucketCnt, store, E, nb);

    float* out = (float*)d_out;
    float* y1 = out;
    float* y2 = out + (size_t)n * D;
    float* y3 = out + 2 * (size_t)n * D;

    // layer 1 (ELU)
    gemm<<<tb, 256, 0, stream>>>(graph, wtR1, hrel, n);
    bucket_agg<0><<<nb, 1024, 0, stream>>>(graph, hrel, wtO1, b1, store, bucketCnt, y1, n);
    // layer 2 (ELU)
    gemm<<<tb, 256, 0, stream>>>(y1, wtR2, hrel, n);
    bucket_agg<0><<<nb, 1024, 0, stream>>>(y1, hrel, wtO2, b2, store, bucketCnt, y2, n);
    // layer 3 (sigmoid)
    gemm<<<tb, 256, 0, stream>>>(y2, wtR3, hrel, n);
    bucket_agg<1><<<nb, 1024, 0, stream>>>(y2, hrel, wtO3, b3, store, bucketCnt, y3, n);
}

// Round 9
// 316.478 us; speedup vs baseline: 5.6628x; 5.6628x over previous
//
#include <hip/hip_runtime.h>
#include <hip/hip_bf16.h>
#include <math.h>

// ---------------------------------------------------------------------------
// three_gcn round 9: R7 structure (bucket CSR + per-layer gemm_ro/agg_act).
//   - R8's LDS-atomic fused agg REVERTED (548us/layer: 80M ds_add_f32 with
//     8-way bank aliasing; VALUBusy 1.5%).
//   - CSR records packed to 4B: (d&511)<<17 | src. Halves scatter writes,
//     build reads, and build LDS (64->32KB: occupancy 2->4 blocks/CU).
//   - agg_act: 2 nodes per wave (16 gathers in flight vs 8; gather was
//     latency-bound), OOB edges -> zero row hrel[n] (no clamp/mask ALU).
// ---------------------------------------------------------------------------

#define D 64
#define BSHIFT 9
#define BW 512          // dsts per bucket
#define BCAP 8192       // edge capacity per bucket (mean 6400, +22 sigma)

typedef __attribute__((ext_vector_type(8))) short short8;
typedef __attribute__((ext_vector_type(4))) float f32x4;

__device__ __forceinline__ ushort f2b(float f) {
    uint x = __float_as_uint(f);
    uint r = (x + 0x7fffu + ((x >> 16) & 1u)) >> 16;   // RNE
    return (ushort)r;
}

// ---------------- weight convert + bucketCnt zero + hrel zero row ----------

__global__ __launch_bounds__(256) void convert_w(const float* __restrict__ w0,
                                                 const float* __restrict__ w1,
                                                 const float* __restrict__ w2,
                                                 const float* __restrict__ w3,
                                                 const float* __restrict__ w4,
                                                 const float* __restrict__ w5,
                                                 ushort* __restrict__ out,
                                                 int* __restrict__ bucketCnt,
                                                 ushort* __restrict__ hrel_zrow) {
    if (blockIdx.x == 0 && threadIdx.x < 256) bucketCnt[threadIdx.x] = 0;
    if (blockIdx.x == 1 && threadIdx.x < 32) ((uint*)hrel_zrow)[threadIdx.x] = 0;
    int m = blockIdx.x >> 4;
    int t = (blockIdx.x & 15) * 256 + threadIdx.x;   // 0..4095
    const float* src = m == 0 ? w0 : m == 1 ? w1 : m == 2 ? w2 : m == 3 ? w3 : m == 4 ? w4 : w5;
    int k = t >> 6, d = t & 63;
    out[m * 4096 + d * 64 + k] = f2b(src[t]);
}

// ---------------- CSR pass 1: bucket scatter (4B packed records) ----------

__global__ __launch_bounds__(1024) void bucket_scatter(const int* __restrict__ src,
                                                       const int* __restrict__ dst,
                                                       int* __restrict__ bucketCnt,
                                                       uint* __restrict__ store,
                                                       int E) {
    __shared__ int h[256], base[256], cur[256];
    int t = threadIdx.x;
    if (t < 256) { h[t] = 0; cur[t] = 0; }
    __syncthreads();
    int e = blockIdx.x * 1024 + t;
    uint rec = 0; int b = 0;
    bool ok = e < E;
    if (ok) {
        int s = src[e];
        int d = dst[e];
        b = d >> BSHIFT;
        rec = ((uint)(d & (BW - 1)) << 17) | (uint)s;
        atomicAdd(&h[b], 1);
    }
    __syncthreads();
    if (t < 256) base[t] = h[t] ? atomicAdd(&bucketCnt[t], h[t]) : 0;
    __syncthreads();
    if (ok) {
        int r = atomicAdd(&cur[b], 1);
        int pos = base[b] + r;
        if (pos < BCAP)
            store[(size_t)b * BCAP + pos] = rec;
    }
}

// ---------------- CSR pass 1.5: scan bucket sizes ----------------

__global__ __launch_bounds__(256) void scan_buckets(const int* __restrict__ bucketCnt,
                                                    int* __restrict__ bucketBase,
                                                    int* __restrict__ offs,
                                                    int nb, int n, int E) {
    __shared__ int tmp[256];
    int t = threadIdx.x;
    int v = (t < nb) ? bucketCnt[t] : 0;
    tmp[t] = v;
    __syncthreads();
    for (int off = 1; off < 256; off <<= 1) {
        int add = (t >= off) ? tmp[t - off] : 0;
        __syncthreads();
        tmp[t] += add;
        __syncthreads();
    }
    if (t < nb) bucketBase[t] = tmp[t] - v;
    if (t == 0) offs[n] = E;
}

// ---------------- CSR pass 2: per-bucket counting sort (4B records) -------

__global__ __launch_bounds__(1024) void bucket_build(const int* __restrict__ bucketCnt,
                                                     const int* __restrict__ bucketBase,
                                                     const uint* __restrict__ store,
                                                     int* __restrict__ offs,
                                                     int* __restrict__ src_sorted, int n) {
    __shared__ int h[BW], loc[BW], cur[BW];
    __shared__ uint se[BCAP];                        // 32 KB
    int b = blockIdx.x, t = threadIdx.x;
    int cnt = bucketCnt[b];
    if (cnt > BCAP) cnt = BCAP;
    int obase = bucketBase[b];
    int d0 = b << BSHIFT;
    int nd = n - d0;
    if (nd > BW) nd = BW;
    if (t < BW) { h[t] = 0; cur[t] = 0; }
    __syncthreads();
    for (int i = t; i < cnt; i += 1024) {
        uint p = store[(size_t)b * BCAP + i];
        se[i] = p;
        atomicAdd(&h[p >> 17], 1);
    }
    __syncthreads();
    if (t < BW) loc[t] = h[t];
    __syncthreads();
    for (int off = 1; off < BW; off <<= 1) {
        int add = (t < BW && t >= off) ? loc[t - off] : 0;
        __syncthreads();
        if (t < BW) loc[t] += add;
        __syncthreads();
    }
    if (t < nd) offs[d0 + t] = obase + loc[t] - h[t];   // exclusive
    __syncthreads();
    for (int i = t; i < cnt; i += 1024) {
        uint p = se[i];
        int dl = p >> 17;
        int r = atomicAdd(&cur[dl], 1);
        src_sorted[obase + loc[dl] - h[dl] + r] = (int)(p & 0x1FFFFu);
    }
}

// ---------------- gemm_ro: h_rel = x@Wr (bf16), h_root = x@Wo + b (bf16) ----

__global__ __launch_bounds__(256) void gemm_ro(const float* __restrict__ x,
                                               const ushort* __restrict__ WtR,
                                               const ushort* __restrict__ WtO,
                                               const float* __restrict__ bias,
                                               ushort* __restrict__ hrel,
                                               ushort* __restrict__ hroot, int n) {
    __shared__ ushort hsR[4][16 * 64];
    __shared__ ushort hsO[4][16 * 64];
    int t = threadIdx.x;
    int w = t >> 6, l = t & 63;
    int i0 = blockIdx.x * 64 + w * 16;
    int lr = l & 15, kb = l >> 4;
    int row = i0 + lr;
    int rowc = row < n ? row : n - 1;

    short8 a[2];
#pragma unroll
    for (int s = 0; s < 2; ++s) {
        const float* p = x + (size_t)rowc * D + s * 32 + kb * 8;
        float4 u = *(const float4*)p;
        float4 v = *(const float4*)(p + 4);
        a[s][0] = f2b(u.x); a[s][1] = f2b(u.y); a[s][2] = f2b(u.z); a[s][3] = f2b(u.w);
        a[s][4] = f2b(v.x); a[s][5] = f2b(v.y); a[s][6] = f2b(v.z); a[s][7] = f2b(v.w);
    }

#pragma unroll
    for (int ct = 0; ct < 4; ++ct) {
        f32x4 accR = (f32x4){0.f, 0.f, 0.f, 0.f};
        f32x4 accO = (f32x4){0.f, 0.f, 0.f, 0.f};
#pragma unroll
        for (int s = 0; s < 2; ++s) {
            short8 bR = *(const short8*)(WtR + (ct * 16 + lr) * D + s * 32 + kb * 8);
            short8 bO = *(const short8*)(WtO + (ct * 16 + lr) * D + s * 32 + kb * 8);
            accR = __builtin_amdgcn_mfma_f32_16x16x32_bf16(a[s], bR, accR, 0, 0, 0);
            accO = __builtin_amdgcn_mfma_f32_16x16x32_bf16(a[s], bO, accO, 0, 0, 0);
        }
        float bv = bias[ct * 16 + lr];
#pragma unroll
        for (int i = 0; i < 4; ++i) {
            hsR[w][(kb * 4 + i) * 64 + ct * 16 + lr] = f2b(accR[i]);
            hsO[w][(kb * 4 + i) * 64 + ct * 16 + lr] = f2b(accO[i] + bv);
        }
    }
    __syncthreads();

    int r = l >> 2, ch = l & 3;
    int grow = i0 + r;
    if (grow < n) {
        const float4* spR = (const float4*)&hsR[w][r * 64 + ch * 16];
        const float4* spO = (const float4*)&hsO[w][r * 64 + ch * 16];
        float4 r0 = spR[0];
        float4 r1 = spR[1];
        float4 o0 = spO[0];
        float4 o1 = spO[1];
        *(float4*)(hrel + (size_t)grow * D + ch * 16) = r0;
        *(float4*)(hrel + (size_t)grow * D + ch * 16 + 8) = r1;
        *(float4*)(hroot + (size_t)grow * D + ch * 16) = o0;
        *(float4*)(hroot + (size_t)grow * D + ch * 16 + 8) = o1;
    }
}

// ---------------- agg_act: y = act(sum h_rel[src] + h_root) -----------------
// TWO nodes per wave (A,B): 16 independent gather loads in flight (gather is
// latency-bound). Lane role: q=l>>4 edge residue mod 4, r=l&15 dims 4r..4r+3.
// OOB edge slots load the zero row hrel[n] (no mask ALU); src_sorted has 16
// slack entries so the tail index read is in-bounds.

template <int ACT>
__global__ __launch_bounds__(256) void agg_act(const ushort* __restrict__ hrel,
                                               const ushort* __restrict__ hroot,
                                               const int* __restrict__ offs,
                                               const int* __restrict__ srcs,
                                               float* __restrict__ y, int n) {
    int nA = blockIdx.x * 8 + (threadIdx.x >> 6) * 2;
    int l = threadIdx.x & 63;
    if (nA >= n) return;
    int nB = nA + 1;
    bool hasB = nB < n;
    int q = l >> 4, r = l & 15;

    int oA = offs[nA];
    int oB = offs[nA + 1];
    int oC = hasB ? offs[nA + 2] : oB;

    float a0 = 0.f, a1 = 0.f, a2 = 0.f, a3 = 0.f;
    float b0 = 0.f, b1 = 0.f, b2 = 0.f, b3 = 0.f;

    int eA = oA, eB = oB;
    while (eA < oB || eB < oC) {
#pragma unroll
        for (int k = 0; k < 4; ++k) {
            int ia = eA + k * 4 + q;
            int ib = eB + k * 4 + q;
            int sA = (ia < oB) ? srcs[ia] : n;       // slack read, zero row
            int sB = (ib < oC) ? srcs[ib] : n;
            uint2 uA = *(const uint2*)(hrel + (size_t)sA * D + r * 4);
            uint2 uB = *(const uint2*)(hrel + (size_t)sB * D + r * 4);
            a0 += __uint_as_float(uA.x << 16);
            a1 += __uint_as_float(uA.x & 0xffff0000u);
            a2 += __uint_as_float(uA.y << 16);
            a3 += __uint_as_float(uA.y & 0xffff0000u);
            b0 += __uint_as_float(uB.x << 16);
            b1 += __uint_as_float(uB.x & 0xffff0000u);
            b2 += __uint_as_float(uB.y << 16);
            b3 += __uint_as_float(uB.y & 0xffff0000u);
        }
        eA += 16; eB += 16;
    }

    a0 += __shfl_xor(a0, 32); a0 += __shfl_xor(a0, 16);
    a1 += __shfl_xor(a1, 32); a1 += __shfl_xor(a1, 16);
    a2 += __shfl_xor(a2, 32); a2 += __shfl_xor(a2, 16);
    a3 += __shfl_xor(a3, 32); a3 += __shfl_xor(a3, 16);
    b0 += __shfl_xor(b0, 32); b0 += __shfl_xor(b0, 16);
    b1 += __shfl_xor(b1, 32); b1 += __shfl_xor(b1, 16);
    b2 += __shfl_xor(b2, 32); b2 += __shfl_xor(b2, 16);
    b3 += __shfl_xor(b3, 32); b3 += __shfl_xor(b3, 16);

    // lanes q==0 finalize node A, q==1 finalize node B
    if (q < 2 && (q == 0 || hasB)) {
        int node = q == 0 ? nA : nB;
        float v0 = q == 0 ? a0 : b0;
        float v1 = q == 0 ? a1 : b1;
        float v2 = q == 0 ? a2 : b2;
        float v3 = q == 0 ? a3 : b3;
        uint2 hr = *(const uint2*)(hroot + (size_t)node * D + r * 4);
        v0 += __uint_as_float(hr.x << 16);
        v1 += __uint_as_float(hr.x & 0xffff0000u);
        v2 += __uint_as_float(hr.y << 16);
        v3 += __uint_as_float(hr.y & 0xffff0000u);
        if (ACT == 0) {
            v0 = v0 > 0.f ? v0 : __expf(v0) - 1.f;
            v1 = v1 > 0.f ? v1 : __expf(v1) - 1.f;
            v2 = v2 > 0.f ? v2 : __expf(v2) - 1.f;
            v3 = v3 > 0.f ? v3 : __expf(v3) - 1.f;
        } else {
            v0 = __builtin_amdgcn_rcpf(1.f + __expf(-v0));
            v1 = __builtin_amdgcn_rcpf(1.f + __expf(-v1));
            v2 = __builtin_amdgcn_rcpf(1.f + __expf(-v2));
            v3 = __builtin_amdgcn_rcpf(1.f + __expf(-v3));
        }
        float4 o; o.x = v0; o.y = v1; o.z = v2; o.w = v3;
        *(float4*)(y + (size_t)node * D + r * 4) = o;
    }
}

// ---------------- launch ----------------

extern "C" void kernel_launch(void* const* d_in, const int* in_sizes, int n_in,
                              void* d_out, int out_size, void* d_ws, size_t ws_size,
                              hipStream_t stream) {
    const float* graph = (const float*)d_in[0];
    const int* eidx    = (const int*)d_in[1];
    const float* W1r = (const float*)d_in[2];
    const float* W1o = (const float*)d_in[3];
    const float* b1  = (const float*)d_in[4];
    const float* W2r = (const float*)d_in[5];
    const float* W2o = (const float*)d_in[6];
    const float* b2  = (const float*)d_in[7];
    const float* W3r = (const float*)d_in[8];
    const float* W3o = (const float*)d_in[9];
    const float* b3  = (const float*)d_in[10];

    int n = in_sizes[0] / D;     // 100000
    int E = in_sizes[1] / 2;     // 1250000
    const int* src  = eidx;
    const int* dstl = eidx + E;
    int nb = (n + BW - 1) >> BSHIFT;   // 196

    char* w = (char*)d_ws;
    auto carve = [&](size_t bytes) {
        void* p = (void*)w;
        w += (bytes + 255) & ~(size_t)255;
        return p;
    };
    ushort* hrel  = (ushort*)carve((size_t)(n + 1) * D * sizeof(ushort)); // +zero row
    ushort* hroot = (ushort*)carve((size_t)n * D * sizeof(ushort));
    // bucket store aliases hrel+hroot (dead during CSR build): 196*8192*4 = 6.4 MB
    uint* store = (uint*)hrel;
    int* offs       = (int*)carve((size_t)(n + 1) * sizeof(int));
    int* src_sorted = (int*)carve((size_t)(E + 16) * sizeof(int));    // 16 slack
    int* bucketCnt  = (int*)carve(256 * sizeof(int));
    int* bucketBase = (int*)carve(256 * sizeof(int));
    ushort* wt      = (ushort*)carve(6 * 4096 * sizeof(ushort));      // 48 KB
    ushort* wtR1 = wt;
    ushort* wtO1 = wt + 1 * 4096;
    ushort* wtR2 = wt + 2 * 4096;
    ushort* wtO2 = wt + 3 * 4096;
    ushort* wtR3 = wt + 4 * 4096;
    ushort* wtO3 = wt + 5 * 4096;

    int eb1 = (E + 1023) / 1024;   // 1221
    int tb  = (n + 63) / 64;       // 1563
    int ab  = (n + 7) / 8;         // 12500

    convert_w<<<96, 256, 0, stream>>>(W1r, W1o, W2r, W2o, W3r, W3o, wt, bucketCnt,
                                      hrel + (size_t)n * D);
    bucket_scatter<<<eb1, 1024, 0, stream>>>(src, dstl, bucketCnt, store, E);
    scan_buckets<<<1, 256, 0, stream>>>(bucketCnt, bucketBase, offs, nb, n, E);
    bucket_build<<<nb, 1024, 0, stream>>>(bucketCnt, bucketBase, store, offs, src_sorted, n);

    float* out = (float*)d_out;
    float* y1 = out;
    float* y2 = out + (size_t)n * D;
    float* y3 = out + 2 * (size_t)n * D;

    // NOTE: gemm_ro overwrites hrel (aliased with store) — store is dead by then,
    // but the zero row hrel[n] (written in convert_w) is beyond store's 6.4MB
    // footprint only if n*D*2 > MAXNB*BCAP*4; 12.8MB > 6.4MB ✓ (row n at 12.8MB).

    // layer 1 (ELU)
    gemm_ro<<<tb, 256, 0, stream>>>(graph, wtR1, wtO1, b1, hrel, hroot, n);
    agg_act<0><<<ab, 256, 0, stream>>>(hrel, hroot, offs, src_sorted, y1, n);
    // layer 2 (ELU)
    gemm_ro<<<tb, 256, 0, stream>>>(y1, wtR2, wtO2, b2, hrel, hroot, n);
    agg_act<0><<<ab, 256, 0, stream>>>(hrel, hroot, offs, src_sorted, y2, n);
    // layer 3 (sigmoid)
    gemm_ro<<<tb, 256, 0, stream>>>(y2, wtR3, wtO3, b3, hrel, hroot, n);
    agg_act<1><<<ab, 256, 0, stream>>>(hrel, hroot, offs, src_sorted, y3, n);
}

// Round 11
// 313.710 us; speedup vs baseline: 5.7128x; 1.0088x over previous
//
#include <hip/hip_runtime.h>
#include <hip/hip_bf16.h>
#include <math.h>

// ---------------------------------------------------------------------------
// three_gcn round 10 (resubmit; R10 bench was GPUAcquisitionTimeout):
//   - scatter_gemm: one launch, blocks [0,SB) bucket-scatter edges (256thr,
//     1024 edges/blk), blocks [SB,SB+TB) run layer-1 gemm_ro. Independent
//     work overlapped; store lives in d_out's y3 region (dead until agg3)
//     so it no longer aliases hrel.
//   - bucket_build self-scans bucket counts (scan_buckets dispatch deleted).
//   - agg_act: hroot uint2 prefetched above the edge loop (was serialized
//     after the fold inside the q<2 branch: ~700cy exposed per wave).
// ---------------------------------------------------------------------------

#define D 64
#define BSHIFT 9
#define BW 512          // dsts per bucket
#define BCAP 8192       // edge capacity per bucket (mean 6400, +22 sigma)

typedef __attribute__((ext_vector_type(8))) short short8;
typedef __attribute__((ext_vector_type(4))) float f32x4;

__device__ __forceinline__ ushort f2b(float f) {
    uint x = __float_as_uint(f);
    uint r = (x + 0x7fffu + ((x >> 16) & 1u)) >> 16;   // RNE
    return (ushort)r;
}

// ---------------- weight convert + bucketCnt zero + hrel zero row ----------

__global__ __launch_bounds__(256) void convert_w(const float* __restrict__ w0,
                                                 const float* __restrict__ w1,
                                                 const float* __restrict__ w2,
                                                 const float* __restrict__ w3,
                                                 const float* __restrict__ w4,
                                                 const float* __restrict__ w5,
                                                 ushort* __restrict__ out,
                                                 int* __restrict__ bucketCnt,
                                                 ushort* __restrict__ hrel_zrow) {
    if (blockIdx.x == 0 && threadIdx.x < 256) bucketCnt[threadIdx.x] = 0;
    if (blockIdx.x == 1 && threadIdx.x < 32) ((uint*)hrel_zrow)[threadIdx.x] = 0;
    int m = blockIdx.x >> 4;
    int t = (blockIdx.x & 15) * 256 + threadIdx.x;   // 0..4095
    const float* src = m == 0 ? w0 : m == 1 ? w1 : m == 2 ? w2 : m == 3 ? w3 : m == 4 ? w4 : w5;
    int k = t >> 6, d = t & 63;
    out[m * 4096 + d * 64 + k] = f2b(src[t]);
}

// ---------------- gemm_ro body (shared by fused + standalone) ----------------

__device__ __forceinline__ void gemm_ro_body(int blk, int t,
                                             const float* __restrict__ x,
                                             const ushort* __restrict__ WtR,
                                             const ushort* __restrict__ WtO,
                                             const float* __restrict__ bias,
                                             ushort* __restrict__ hrel,
                                             ushort* __restrict__ hroot, int n,
                                             ushort* hsR, ushort* hsO) {
    int w = t >> 6, l = t & 63;
    int i0 = blk * 64 + w * 16;
    int lr = l & 15, kb = l >> 4;
    int row = i0 + lr;
    int rowc = row < n ? row : n - 1;

    short8 a[2];
#pragma unroll
    for (int s = 0; s < 2; ++s) {
        const float* p = x + (size_t)rowc * D + s * 32 + kb * 8;
        float4 u = *(const float4*)p;
        float4 v = *(const float4*)(p + 4);
        a[s][0] = f2b(u.x); a[s][1] = f2b(u.y); a[s][2] = f2b(u.z); a[s][3] = f2b(u.w);
        a[s][4] = f2b(v.x); a[s][5] = f2b(v.y); a[s][6] = f2b(v.z); a[s][7] = f2b(v.w);
    }

    ushort* hR = hsR + w * 16 * 64;
    ushort* hO = hsO + w * 16 * 64;
#pragma unroll
    for (int ct = 0; ct < 4; ++ct) {
        f32x4 accR = (f32x4){0.f, 0.f, 0.f, 0.f};
        f32x4 accO = (f32x4){0.f, 0.f, 0.f, 0.f};
#pragma unroll
        for (int s = 0; s < 2; ++s) {
            short8 bR = *(const short8*)(WtR + (ct * 16 + lr) * D + s * 32 + kb * 8);
            short8 bO = *(const short8*)(WtO + (ct * 16 + lr) * D + s * 32 + kb * 8);
            accR = __builtin_amdgcn_mfma_f32_16x16x32_bf16(a[s], bR, accR, 0, 0, 0);
            accO = __builtin_amdgcn_mfma_f32_16x16x32_bf16(a[s], bO, accO, 0, 0, 0);
        }
        float bv = bias[ct * 16 + lr];
#pragma unroll
        for (int i = 0; i < 4; ++i) {
            hR[(kb * 4 + i) * 64 + ct * 16 + lr] = f2b(accR[i]);
            hO[(kb * 4 + i) * 64 + ct * 16 + lr] = f2b(accO[i] + bv);
        }
    }
    __syncthreads();

    int r = l >> 2, ch = l & 3;
    int grow = i0 + r;
    if (grow < n) {
        const float4* spR = (const float4*)&hR[r * 64 + ch * 16];
        const float4* spO = (const float4*)&hO[r * 64 + ch * 16];
        float4 r0 = spR[0];
        float4 r1 = spR[1];
        float4 o0 = spO[0];
        float4 o1 = spO[1];
        *(float4*)(hrel + (size_t)grow * D + ch * 16) = r0;
        *(float4*)(hrel + (size_t)grow * D + ch * 16 + 8) = r1;
        *(float4*)(hroot + (size_t)grow * D + ch * 16) = o0;
        *(float4*)(hroot + (size_t)grow * D + ch * 16 + 8) = o1;
    }
}

__global__ __launch_bounds__(256) void gemm_ro(const float* __restrict__ x,
                                               const ushort* __restrict__ WtR,
                                               const ushort* __restrict__ WtO,
                                               const float* __restrict__ bias,
                                               ushort* __restrict__ hrel,
                                               ushort* __restrict__ hroot, int n) {
    __shared__ ushort hsR[4 * 16 * 64];
    __shared__ ushort hsO[4 * 16 * 64];
    gemm_ro_body(blockIdx.x, threadIdx.x, x, WtR, WtO, bias, hrel, hroot, n, hsR, hsO);
}

// ---------------- fused: bucket scatter (blocks < SB) | gemm1 (rest) --------
// scatter: 256 threads, 1024 edges/block, 4B records (d&511)<<17 | src.

__global__ __launch_bounds__(256) void scatter_gemm(const int* __restrict__ esrc,
                                                    const int* __restrict__ edst,
                                                    int* __restrict__ bucketCnt,
                                                    uint* __restrict__ store,
                                                    int E, int SB,
                                                    const float* __restrict__ x,
                                                    const ushort* __restrict__ WtR,
                                                    const ushort* __restrict__ WtO,
                                                    const float* __restrict__ bias,
                                                    ushort* __restrict__ hrel,
                                                    ushort* __restrict__ hroot, int n) {
    __shared__ ushort hsR[4 * 16 * 64];   // 8KB, reused as scatter LDS
    int t = threadIdx.x;
    int bx = blockIdx.x;
    if (bx >= SB) {
        __shared__ ushort hsO[4 * 16 * 64];
        gemm_ro_body(bx - SB, t, x, WtR, WtO, bias, hrel, hroot, n, hsR, hsO);
        return;
    }
    // ---- scatter ----
    int* h    = (int*)hsR;          // [256]
    int* base = h + 256;
    int* cur  = base + 256;
    if (t < 256) { h[t] = 0; cur[t] = 0; }
    __syncthreads();
    int e0 = bx * 1024;
    uint rec[4]; int bb[4];
#pragma unroll
    for (int i = 0; i < 4; ++i) {
        int e = e0 + i * 256 + t;
        if (e < E) {
            int s = esrc[e];
            int d = edst[e];
            bb[i] = d >> BSHIFT;
            rec[i] = ((uint)(d & (BW - 1)) << 17) | (uint)s;
            atomicAdd(&h[bb[i]], 1);
        } else bb[i] = -1;
    }
    __syncthreads();
    base[t] = h[t] ? atomicAdd(&bucketCnt[t], h[t]) : 0;
    __syncthreads();
#pragma unroll
    for (int i = 0; i < 4; ++i) {
        if (bb[i] >= 0) {
            int p = base[bb[i]] + atomicAdd(&cur[bb[i]], 1);
            if (p < BCAP)
                store[(size_t)bb[i] * BCAP + p] = rec[i];
        }
    }
}

// ---------------- bucket_build (self-scanning) ----------------

__global__ __launch_bounds__(1024) void bucket_build(const int* __restrict__ bucketCnt,
                                                     const uint* __restrict__ store,
                                                     int* __restrict__ offs,
                                                     int* __restrict__ src_sorted,
                                                     int n, int nb, int E) {
    __shared__ int h[BW], loc[BW], cur[BW];
    __shared__ int sc[256];
    __shared__ uint se[BCAP];                        // 32 KB
    int b = blockIdx.x, t = threadIdx.x;

    // self-scan of bucket counts (nb <= 256)
    if (t < 256) sc[t] = (t < nb) ? bucketCnt[t] : 0;
    __syncthreads();
    for (int off = 1; off < 256; off <<= 1) {
        int add = (t < 256 && t >= off) ? sc[t - off] : 0;
        __syncthreads();
        if (t < 256) sc[t] += add;
        __syncthreads();
    }
    int obase = sc[b] - bucketCnt[b];               // exclusive prefix
    if (b == 0 && t == 0) offs[n] = E;

    int cnt = bucketCnt[b];
    if (cnt > BCAP) cnt = BCAP;
    int d0 = b << BSHIFT;
    int nd = n - d0;
    if (nd > BW) nd = BW;
    if (t < BW) { h[t] = 0; cur[t] = 0; }
    __syncthreads();
    for (int i = t; i < cnt; i += 1024) {
        uint p = store[(size_t)b * BCAP + i];
        se[i] = p;
        atomicAdd(&h[p >> 17], 1);
    }
    __syncthreads();
    if (t < BW) loc[t] = h[t];
    __syncthreads();
    for (int off = 1; off < BW; off <<= 1) {
        int add = (t < BW && t >= off) ? loc[t - off] : 0;
        __syncthreads();
        if (t < BW) loc[t] += add;
        __syncthreads();
    }
    if (t < nd) offs[d0 + t] = obase + loc[t] - h[t];   // exclusive
    __syncthreads();
    for (int i = t; i < cnt; i += 1024) {
        uint p = se[i];
        int dl = p >> 17;
        int r = atomicAdd(&cur[dl], 1);
        src_sorted[obase + loc[dl] - h[dl] + r] = (int)(p & 0x1FFFFu);
    }
}

// ---------------- agg_act: y = act(sum h_rel[src] + h_root) -----------------
// Two nodes per wave; q=l>>4 edge slot mod 4, r=l&15 dims 4r..4r+3.
// hroot prefetched ABOVE the edge loop (hidden under gathers).

template <int ACT>
__global__ __launch_bounds__(256) void agg_act(const ushort* __restrict__ hrel,
                                               const ushort* __restrict__ hroot,
                                               const int* __restrict__ offs,
                                               const int* __restrict__ srcs,
                                               float* __restrict__ y, int n) {
    int nA = blockIdx.x * 8 + (threadIdx.x >> 6) * 2;
    int l = threadIdx.x & 63;
    if (nA >= n) return;
    int nB = nA + 1;
    bool hasB = nB < n;
    int q = l >> 4, r = l & 15;

    int oA = offs[nA];
    int oB = offs[nA + 1];
    int oC = hasB ? offs[nA + 2] : oB;

    // prefetch root terms (independent of gathers)
    uint2 hrA = *(const uint2*)(hroot + (size_t)nA * D + r * 4);
    uint2 hrB = hasB ? *(const uint2*)(hroot + (size_t)nB * D + r * 4) : hrA;

    float a0 = 0.f, a1 = 0.f, a2 = 0.f, a3 = 0.f;
    float b0 = 0.f, b1 = 0.f, b2 = 0.f, b3 = 0.f;

    int eA = oA, eB = oB;
    while (eA < oB || eB < oC) {
#pragma unroll
        for (int k = 0; k < 4; ++k) {
            int ia = eA + k * 4 + q;
            int ib = eB + k * 4 + q;
            int sA = (ia < oB) ? srcs[ia] : n;       // slack read -> zero row
            int sB = (ib < oC) ? srcs[ib] : n;
            uint2 uA = *(const uint2*)(hrel + (size_t)sA * D + r * 4);
            uint2 uB = *(const uint2*)(hrel + (size_t)sB * D + r * 4);
            a0 += __uint_as_float(uA.x << 16);
            a1 += __uint_as_float(uA.x & 0xffff0000u);
            a2 += __uint_as_float(uA.y << 16);
            a3 += __uint_as_float(uA.y & 0xffff0000u);
            b0 += __uint_as_float(uB.x << 16);
            b1 += __uint_as_float(uB.x & 0xffff0000u);
            b2 += __uint_as_float(uB.y << 16);
            b3 += __uint_as_float(uB.y & 0xffff0000u);
        }
        eA += 16; eB += 16;
    }

    a0 += __shfl_xor(a0, 32); a0 += __shfl_xor(a0, 16);
    a1 += __shfl_xor(a1, 32); a1 += __shfl_xor(a1, 16);
    a2 += __shfl_xor(a2, 32); a2 += __shfl_xor(a2, 16);
    a3 += __shfl_xor(a3, 32); a3 += __shfl_xor(a3, 16);
    b0 += __shfl_xor(b0, 32); b0 += __shfl_xor(b0, 16);
    b1 += __shfl_xor(b1, 32); b1 += __shfl_xor(b1, 16);
    b2 += __shfl_xor(b2, 32); b2 += __shfl_xor(b2, 16);
    b3 += __shfl_xor(b3, 32); b3 += __shfl_xor(b3, 16);

    if (q < 2 && (q == 0 || hasB)) {
        int node = q == 0 ? nA : nB;
        uint2 hr = q == 0 ? hrA : hrB;
        float v0 = (q == 0 ? a0 : b0) + __uint_as_float(hr.x << 16);
        float v1 = (q == 0 ? a1 : b1) + __uint_as_float(hr.x & 0xffff0000u);
        float v2 = (q == 0 ? a2 : b2) + __uint_as_float(hr.y << 16);
        float v3 = (q == 0 ? a3 : b3) + __uint_as_float(hr.y & 0xffff0000u);
        if (ACT == 0) {
            v0 = v0 > 0.f ? v0 : __expf(v0) - 1.f;
            v1 = v1 > 0.f ? v1 : __expf(v1) - 1.f;
            v2 = v2 > 0.f ? v2 : __expf(v2) - 1.f;
            v3 = v3 > 0.f ? v3 : __expf(v3) - 1.f;
        } else {
            v0 = __builtin_amdgcn_rcpf(1.f + __expf(-v0));
            v1 = __builtin_amdgcn_rcpf(1.f + __expf(-v1));
            v2 = __builtin_amdgcn_rcpf(1.f + __expf(-v2));
            v3 = __builtin_amdgcn_rcpf(1.f + __expf(-v3));
        }
        float4 o; o.x = v0; o.y = v1; o.z = v2; o.w = v3;
        *(float4*)(y + (size_t)node * D + r * 4) = o;
    }
}

// ---------------- launch ----------------

extern "C" void kernel_launch(void* const* d_in, const int* in_sizes, int n_in,
                              void* d_out, int out_size, void* d_ws, size_t ws_size,
                              hipStream_t stream) {
    const float* graph = (const float*)d_in[0];
    const int* eidx    = (const int*)d_in[1];
    const float* W1r = (const float*)d_in[2];
    const float* W1o = (const float*)d_in[3];
    const float* b1  = (const float*)d_in[4];
    const float* W2r = (const float*)d_in[5];
    const float* W2o = (const float*)d_in[6];
    const float* b2  = (const float*)d_in[7];
    const float* W3r = (const float*)d_in[8];
    const float* W3o = (const float*)d_in[9];
    const float* b3  = (const float*)d_in[10];

    int n = in_sizes[0] / D;     // 100000
    int E = in_sizes[1] / 2;     // 1250000
    const int* esrc = eidx;
    const int* edst = eidx + E;
    int nb = (n + BW - 1) >> BSHIFT;   // 196

    char* w = (char*)d_ws;
    auto carve = [&](size_t bytes) {
        void* p = (void*)w;
        w += (bytes + 255) & ~(size_t)255;
        return p;
    };
    ushort* hrel  = (ushort*)carve((size_t)(n + 1) * D * sizeof(ushort)); // +zero row
    ushort* hroot = (ushort*)carve((size_t)n * D * sizeof(ushort));
    int* offs       = (int*)carve((size_t)(n + 1) * sizeof(int));
    int* src_sorted = (int*)carve((size_t)(E + 16) * sizeof(int));    // 16 slack
    int* bucketCnt  = (int*)carve(256 * sizeof(int));
    ushort* wt      = (ushort*)carve(6 * 4096 * sizeof(ushort));      // 48 KB
    ushort* wtR1 = wt;
    ushort* wtO1 = wt + 1 * 4096;
    ushort* wtR2 = wt + 2 * 4096;
    ushort* wtO2 = wt + 3 * 4096;
    ushort* wtR3 = wt + 4 * 4096;
    ushort* wtO3 = wt + 5 * 4096;

    float* out = (float*)d_out;
    float* y1 = out;
    float* y2 = out + (size_t)n * D;
    float* y3 = out + 2 * (size_t)n * D;
    // bucket store lives in the y3 region (dead until agg3; 6.4MB <= 25.6MB)
    uint* store = (uint*)y3;

    int SB = (E + 1023) / 1024;    // 1221 scatter blocks
    int tb = (n + 63) / 64;        // 1563 gemm blocks
    int ab = (n + 7) / 8;          // 12500

    convert_w<<<96, 256, 0, stream>>>(W1r, W1o, W2r, W2o, W3r, W3o, wt, bucketCnt,
                                      hrel + (size_t)n * D);
    // scatter ∥ layer-1 gemm (independent)
    scatter_gemm<<<SB + tb, 256, 0, stream>>>(esrc, edst, bucketCnt, store, E, SB,
                                              graph, wtR1, wtO1, b1, hrel, hroot, n);
    bucket_build<<<nb, 1024, 0, stream>>>(bucketCnt, store, offs, src_sorted, n, nb, E);

    // layer 1 (ELU)
    agg_act<0><<<ab, 256, 0, stream>>>(hrel, hroot, offs, src_sorted, y1, n);
    // layer 2 (ELU)
    gemm_ro<<<tb, 256, 0, stream>>>(y1, wtR2, wtO2, b2, hrel, hroot, n);
    agg_act<0><<<ab, 256, 0, stream>>>(hrel, hroot, offs, src_sorted, y2, n);
    // layer 3 (sigmoid)
    gemm_ro<<<tb, 256, 0, stream>>>(y2, wtR3, wtO3, b3, hrel, hroot, n);
    agg_act<1><<<ab, 256, 0, stream>>>(hrel, hroot, offs, src_sorted, y3, n);
}